// Round 11
// baseline (345.574 us; speedup 1.0000x reference)
//
#include <hip/hip_runtime.h>
#include <cstdint>

namespace {

typedef __attribute__((ext_vector_type(8))) short bf16x8;
typedef __attribute__((ext_vector_type(4))) short bf16x4;
typedef __attribute__((ext_vector_type(4))) float f32x4;

constexpr int D  = 1024;
constexpr int H  = 16;
constexpr int DH = 64;
constexpr int B  = 2;
constexpr int S  = 2048;
constexpr int M  = B * S;          // 4096
// 1/sqrt(64) * log2(e): QK^T logits land pre-scaled for exp2
constexpr float SCALE_Q = 0.125f * 1.4426950408889634f;

__device__ inline unsigned short f2bf(float f) {
    union { float f; uint32_t u; } v{f};
    return (unsigned short)((v.u + 0x7fffu + ((v.u >> 16) & 1u)) >> 16);
}

__device__ inline void gload16(const void* g, void* l) {
    __builtin_amdgcn_global_load_lds(
        (const __attribute__((address_space(1))) void*)g,
        (__attribute__((address_space(3))) void*)l, 16, 0, 0);
}

// ---------------------------------------------------------------------------
// x [4096,1024] f32 -> bf16
// ---------------------------------------------------------------------------
__global__ __launch_bounds__(256) void pack_x(const float* __restrict__ x,
                                              unsigned short* __restrict__ xb) {
    const int i = (blockIdx.x * 256 + threadIdx.x) * 8;
    float4 a = *reinterpret_cast<const float4*>(&x[i]);
    float4 b = *reinterpret_cast<const float4*>(&x[i + 4]);
    bf16x8 o;
    o[0] = f2bf(a.x); o[1] = f2bf(a.y); o[2] = f2bf(a.z); o[3] = f2bf(a.w);
    o[4] = f2bf(b.x); o[5] = f2bf(b.y); o[6] = f2bf(b.z); o[7] = f2bf(b.w);
    *reinterpret_cast<bf16x8*>(&xb[i]) = o;
}

// ---------------------------------------------------------------------------
// 4 weight matrices [1024 k][1024 n] f32 -> WtAll bf16 [4][n][k]
// ---------------------------------------------------------------------------
__global__ __launch_bounds__(256) void transpose_w4(
    const float* __restrict__ W0, const float* __restrict__ W1,
    const float* __restrict__ W2, const float* __restrict__ W3,
    unsigned short* __restrict__ WtAll)
{
    __shared__ unsigned short T[64][72];
    const int z = blockIdx.z;
    const float* W = z == 0 ? W0 : (z == 1 ? W1 : (z == 2 ? W2 : W3));
    unsigned short* Wt = WtAll + (size_t)z * D * D;
    const int n0 = blockIdx.x * 64, k0 = blockIdx.y * 64;
    const int t = threadIdx.x;
    #pragma unroll
    for (int i = 0; i < 16; ++i) {
        int idx = i * 256 + t, r = idx >> 6, c = idx & 63;
        T[r][c] = f2bf(W[(size_t)(k0 + r) * D + n0 + c]);
    }
    __syncthreads();
    #pragma unroll
    for (int i = 0; i < 16; ++i) {
        int idx = i * 256 + t, r = idx >> 6, c = idx & 63;
        Wt[(size_t)(n0 + r) * D + k0 + c] = T[c][r];
    }
}

// ---------------------------------------------------------------------------
// Heterogeneous QKV dispatch, m97 GEMM structure.
//   blocks [0,768):    C = A @ Wt^T + bias for Q|K|V (128x128 tiles);
//                      Q scaled SCALE_Q; V written transposed [bh][dh][s].
//   blocks [768,1280): zero-fill of P's strictly-upper 64x64 tiles
//                      (write-only work hidden under the compute-bound GEMM;
//                       strips paired (qt, 31-qt) -> constant 31 tiles/block).
// ---------------------------------------------------------------------------
__global__ __launch_bounds__(256) void qkv_zero(
    const unsigned short* __restrict__ A, const unsigned short* __restrict__ Bt,
    const float* __restrict__ b0, const float* __restrict__ b1,
    const float* __restrict__ b2,
    unsigned short* __restrict__ oQ, unsigned short* __restrict__ oK,
    unsigned short* __restrict__ oVt, float* __restrict__ P)
{
    __shared__ __align__(16) unsigned short As[128 * 64];
    __shared__ __align__(16) unsigned short Bs[128 * 64];
    const int id = blockIdx.x;
    const int t = threadIdx.x;
    const int lane = t & 63, w = t >> 6;
    const int lo = lane & 15, hi = lane >> 4;

    if (id >= 768) {
        // ---- zero-fill block: u in [0,512) -> (bh, strip pair qt / 31-qt)
        const int u = id - 768;
        const int bh = u & 31;
        const int qtp = u >> 5;                    // 0..15
        float* Pb = P + (size_t)bh * S * S;
        const f32x4 z = {0.f, 0.f, 0.f, 0.f};
        #pragma unroll
        for (int half = 0; half < 2; ++half) {
            const int qt = half == 0 ? qtp : 31 - qtp;
            const int q0 = qt * 64;
            for (int jt = qt + 1; jt < S / 64; ++jt) {
                #pragma unroll
                for (int rr = 0; rr < 4; ++rr) {
                    const int row = q0 + rr * 16 + (t >> 4);
                    __builtin_nontemporal_store(
                        z, reinterpret_cast<f32x4*>(
                            &Pb[(size_t)row * S + jt * 64 + (t & 15) * 4]));
                }
            }
        }
        return;
    }

    // ---- GEMM block
    const int wr = w >> 1, wc = w & 1;
    const int m0 = (id / 24) * 128, n0 = (id % 24) * 128;

    f32x4 acc[4][4] = {};

    for (int k0 = 0; k0 < D; k0 += 64) {
        #pragma unroll
        for (int i = 0; i < 4; ++i) {
            const int row = i * 32 + w * 8 + (lane >> 3);
            const int gcol = ((lane & 7) * 8) ^ ((row & 7) * 8);  // src pre-swizzle
            gload16(&A[(size_t)(m0 + row) * D + k0 + gcol], &As[i * 2048 + w * 512]);
            gload16(&Bt[(size_t)(n0 + row) * D + k0 + gcol], &Bs[i * 2048 + w * 512]);
        }
        __syncthreads();
        #pragma unroll
        for (int kk = 0; kk < 2; ++kk) {
            bf16x8 a[4], b[4];
            #pragma unroll
            for (int m = 0; m < 4; ++m) {
                const int row = wr * 64 + m * 16 + lo;
                a[m] = *reinterpret_cast<const bf16x8*>(
                    &As[row * 64 + ((kk * 32 + hi * 8) ^ ((row & 7) * 8))]);
            }
            #pragma unroll
            for (int n = 0; n < 4; ++n) {
                const int row = wc * 64 + n * 16 + lo;
                b[n] = *reinterpret_cast<const bf16x8*>(
                    &Bs[row * 64 + ((kk * 32 + hi * 8) ^ ((row & 7) * 8))]);
            }
            #pragma unroll
            for (int m = 0; m < 4; ++m)
                #pragma unroll
                for (int n = 0; n < 4; ++n)
                    acc[m][n] = __builtin_amdgcn_mfma_f32_16x16x32_bf16(a[m], b[n], acc[m][n], 0, 0, 0);
        }
        __syncthreads();
    }

    // acc[m][n][r]: row = m0+wr*64+m*16+hi*4+r, col = n0+wc*64+n*16+lo
    const int which = n0 >> 10;                 // uniform per block
    if (which == 2) {
        // V: write Vt[bh][dh][s] directly; 4 consecutive s per lane -> bf16x4
        #pragma unroll
        for (int m = 0; m < 4; ++m) {
            const int row0 = m0 + wr * 64 + m * 16 + hi * 4;
            const int b_ = row0 >> 11, s_ = row0 & (S - 1);
            #pragma unroll
            for (int n = 0; n < 4; ++n) {
                const int nn = (n0 + wc * 64 + n * 16 + lo) & 1023;
                const int h_ = nn >> 6, dh = nn & 63;
                const float bcol = b2[nn];
                bf16x4 o;
                #pragma unroll
                for (int r = 0; r < 4; ++r) o[r] = (short)f2bf(acc[m][n][r] + bcol);
                *reinterpret_cast<bf16x4*>(
                    &oVt[((size_t)(b_ * H + h_) * DH + dh) * S + s_]) = o;
            }
        }
    } else {
        const float* bs = which == 0 ? b0 : b1;
        unsigned short* op = which == 0 ? oQ : oK;
        const float scale = which == 0 ? SCALE_Q : 1.0f;
        #pragma unroll
        for (int m = 0; m < 4; ++m)
            #pragma unroll
            for (int n = 0; n < 4; ++n) {
                const int nn = (n0 + wc * 64 + n * 16 + lo) & 1023;
                const float bcol = bs[nn];
                const int h_ = nn >> 6, dh = nn & 63;
                #pragma unroll
                for (int r = 0; r < 4; ++r) {
                    const int row = m0 + wr * 64 + m * 16 + hi * 4 + r;
                    const int b_ = row >> 11, s_ = row & (S - 1);
                    op[(((size_t)(b_ * H + h_) * S) + s_) * DH + dh] =
                        f2bf((acc[m][n][r] + bcol) * scale);
                }
            }
    }
}

// ---------------------------------------------------------------------------
// Output projection: fp32 row-major, 128x128 tiles (grid 8 x 32).
// ---------------------------------------------------------------------------
__global__ __launch_bounds__(256) void out_gemm(
    const unsigned short* __restrict__ A, const unsigned short* __restrict__ Bt,
    const float* __restrict__ b0, float* __restrict__ oF)
{
    __shared__ __align__(16) unsigned short As[128 * 64];
    __shared__ __align__(16) unsigned short Bs[128 * 64];
    const int t = threadIdx.x;
    const int lane = t & 63, w = t >> 6;
    const int wr = w >> 1, wc = w & 1;
    const int lo = lane & 15, hi = lane >> 4;
    const int m0 = blockIdx.y * 128, n0 = blockIdx.x * 128;

    f32x4 acc[4][4] = {};

    for (int k0 = 0; k0 < D; k0 += 64) {
        #pragma unroll
        for (int i = 0; i < 4; ++i) {
            const int row = i * 32 + w * 8 + (lane >> 3);
            const int gcol = ((lane & 7) * 8) ^ ((row & 7) * 8);
            gload16(&A[(size_t)(m0 + row) * D + k0 + gcol], &As[i * 2048 + w * 512]);
            gload16(&Bt[(size_t)(n0 + row) * D + k0 + gcol], &Bs[i * 2048 + w * 512]);
        }
        __syncthreads();
        #pragma unroll
        for (int kk = 0; kk < 2; ++kk) {
            bf16x8 a[4], b[4];
            #pragma unroll
            for (int m = 0; m < 4; ++m) {
                const int row = wr * 64 + m * 16 + lo;
                a[m] = *reinterpret_cast<const bf16x8*>(
                    &As[row * 64 + ((kk * 32 + hi * 8) ^ ((row & 7) * 8))]);
            }
            #pragma unroll
            for (int n = 0; n < 4; ++n) {
                const int row = wc * 64 + n * 16 + lo;
                b[n] = *reinterpret_cast<const bf16x8*>(
                    &Bs[row * 64 + ((kk * 32 + hi * 8) ^ ((row & 7) * 8))]);
            }
            #pragma unroll
            for (int m = 0; m < 4; ++m)
                #pragma unroll
                for (int n = 0; n < 4; ++n)
                    acc[m][n] = __builtin_amdgcn_mfma_f32_16x16x32_bf16(a[m], b[n], acc[m][n], 0, 0, 0);
        }
        __syncthreads();
    }

    #pragma unroll
    for (int m = 0; m < 4; ++m)
        #pragma unroll
        for (int n = 0; n < 4; ++n) {
            const int col = n0 + wc * 64 + n * 16 + lo;
            const float bcol = b0[col];
            #pragma unroll
            for (int r = 0; r < 4; ++r) {
                const int row = m0 + wr * 64 + m * 16 + hi * 4 + r;
                oF[(size_t)row * D + col] = acc[m][n][r] + bcol;
            }
        }
}

// ---------------------------------------------------------------------------
// Fused attention (Q pre-scaled by log2e -> exp2f; diag tile peeled).
// Sweep 1: row 1/sumexp in registers. Sweep 2: recompute QK^T, normalized P
// via dbuf LDS stage -> coalesced 4-row x 256B nontemporal stores, PV from
// the same LDS tile. Upper-tri zero-fill now lives in qkv_zero.
// ---------------------------------------------------------------------------
__global__ __launch_bounds__(256) void attn_fused(
    const unsigned short* __restrict__ Q, const unsigned short* __restrict__ K,
    const unsigned short* __restrict__ Vt, float* __restrict__ P,
    unsigned short* __restrict__ ctxb)
{
    __shared__ __align__(16) float Pf[2][4][16][68];
    const int bh = blockIdx.x;
    const int qt = (S / 64 - 1) - blockIdx.y;
    const int t = threadIdx.x, lane = t & 63, w = t >> 6;
    const int lo = lane & 15, hi = lane >> 4;
    const int q0 = qt * 64 + w * 16;
    const unsigned short* Qb = Q + (size_t)bh * S * DH;
    const unsigned short* Kb = K + (size_t)bh * S * DH;
    const unsigned short* Vb = Vt + (size_t)bh * DH * S;
    float* Pb = P + (size_t)bh * S * S;

    bf16x8 aq[2];
    #pragma unroll
    for (int kk = 0; kk < 2; ++kk)
        aq[kk] = *reinterpret_cast<const bf16x8*>(&Qb[(size_t)(q0 + lo) * DH + kk * 32 + hi * 8]);

    // ---- sweep 1: row sums (registers only); diag tile peeled
    float li[4];
    {
        float rsum[4] = {0.f, 0.f, 0.f, 0.f};
        for (int jt = 0; jt < qt; ++jt) {         // mask-free main loop
            f32x4 acc[4] = {};
            #pragma unroll
            for (int kk = 0; kk < 2; ++kk)
                #pragma unroll
                for (int n = 0; n < 4; ++n) {
                    bf16x8 bk = *reinterpret_cast<const bf16x8*>(
                        &Kb[(size_t)(jt * 64 + n * 16 + lo) * DH + kk * 32 + hi * 8]);
                    acc[n] = __builtin_amdgcn_mfma_f32_16x16x32_bf16(aq[kk], bk, acc[n], 0, 0, 0);
                }
            #pragma unroll
            for (int n = 0; n < 4; ++n)
                #pragma unroll
                for (int r = 0; r < 4; ++r) rsum[r] += exp2f(acc[n][r]);
        }
        {   // diag tile (jt == qt), masked
            f32x4 acc[4] = {};
            #pragma unroll
            for (int kk = 0; kk < 2; ++kk)
                #pragma unroll
                for (int n = 0; n < 4; ++n) {
                    bf16x8 bk = *reinterpret_cast<const bf16x8*>(
                        &Kb[(size_t)(qt * 64 + n * 16 + lo) * DH + kk * 32 + hi * 8]);
                    acc[n] = __builtin_amdgcn_mfma_f32_16x16x32_bf16(aq[kk], bk, acc[n], 0, 0, 0);
                }
            #pragma unroll
            for (int n = 0; n < 4; ++n) {
                const int j = qt * 64 + n * 16 + lo;
                #pragma unroll
                for (int r = 0; r < 4; ++r) {
                    const float e = exp2f(acc[n][r]);
                    rsum[r] += (j > q0 + hi * 4 + r) ? 0.f : e;
                }
            }
        }
        #pragma unroll
        for (int r = 0; r < 4; ++r) {
            #pragma unroll
            for (int off = 1; off < 16; off <<= 1) rsum[r] += __shfl_xor(rsum[r], off);
            li[r] = 1.0f / rsum[r];      // every lane holds its (hi,r) row's sum
        }
    }

    // ---- sweep 2: normalized P + PV context; diag tile peeled
    f32x4 actx[4] = {};

    for (int jt = 0; jt <= qt; ++jt) {
        float (*pf)[68] = Pf[jt & 1][w];
        f32x4 acc[4] = {};
        #pragma unroll
        for (int kk = 0; kk < 2; ++kk)
            #pragma unroll
            for (int n = 0; n < 4; ++n) {
                bf16x8 bk = *reinterpret_cast<const bf16x8*>(
                    &Kb[(size_t)(jt * 64 + n * 16 + lo) * DH + kk * 32 + hi * 8]);
                acc[n] = __builtin_amdgcn_mfma_f32_16x16x32_bf16(aq[kk], bk, acc[n], 0, 0, 0);
            }
        if (jt < qt) {                            // mask-free path
            #pragma unroll
            for (int n = 0; n < 4; ++n)
                #pragma unroll
                for (int r = 0; r < 4; ++r)
                    pf[hi * 4 + r][n * 16 + lo] = exp2f(acc[n][r]) * li[r];
        } else {                                  // diag tile, masked
            #pragma unroll
            for (int n = 0; n < 4; ++n) {
                const int j = qt * 64 + n * 16 + lo;
                #pragma unroll
                for (int r = 0; r < 4; ++r) {
                    const int qrow = q0 + hi * 4 + r;
                    float p = exp2f(acc[n][r]) * li[r];
                    pf[hi * 4 + r][n * 16 + lo] = (j > qrow) ? 0.f : p;
                }
            }
        }
        // coalesced nontemporal f32x4 stores of the 16x64 fp32 tile
        #pragma unroll
        for (int i2 = 0; i2 < 4; ++i2) {
            const int row = i2 * 4 + hi;
            f32x4 v = *reinterpret_cast<const f32x4*>(&pf[row][lo * 4]);
            __builtin_nontemporal_store(
                v, reinterpret_cast<f32x4*>(&Pb[(size_t)(q0 + row) * S + jt * 64 + lo * 4]));
        }
        // PV: A-frag rebuilt from LDS fp32 (row=lo, k=kk*32+hi*8..+8)
        #pragma unroll
        for (int kk = 0; kk < 2; ++kk) {
            const float* src = &pf[lo][kk * 32 + hi * 8];
            float4 f0 = *reinterpret_cast<const float4*>(src);
            float4 f1 = *reinterpret_cast<const float4*>(src + 4);
            bf16x8 pa;
            pa[0] = f2bf(f0.x); pa[1] = f2bf(f0.y); pa[2] = f2bf(f0.z); pa[3] = f2bf(f0.w);
            pa[4] = f2bf(f1.x); pa[5] = f2bf(f1.y); pa[6] = f2bf(f1.z); pa[7] = f2bf(f1.w);
            #pragma unroll
            for (int n2 = 0; n2 < 4; ++n2) {
                bf16x8 bv = *reinterpret_cast<const bf16x8*>(
                    &Vb[(size_t)(n2 * 16 + lo) * S + jt * 64 + kk * 32 + hi * 8]);
                actx[n2] = __builtin_amdgcn_mfma_f32_16x16x32_bf16(pa, bv, actx[n2], 0, 0, 0);
            }
        }
    }

    // ctx -> merged-head bf16 [b*S+q][h*64+dh]
    const int b_ = bh >> 4, h_ = bh & 15;
    #pragma unroll
    for (int n2 = 0; n2 < 4; ++n2)
        #pragma unroll
        for (int r = 0; r < 4; ++r) {
            const int qg = q0 + hi * 4 + r;
            ctxb[((size_t)(b_ * S + qg)) * D + h_ * 64 + n2 * 16 + lo] = f2bf(actx[n2][r]);
        }
}

}  // namespace

extern "C" void kernel_launch(void* const* d_in, const int* in_sizes, int n_in,
                              void* d_out, int out_size, void* d_ws, size_t ws_size,
                              hipStream_t stream) {
    const float* x  = (const float*)d_in[0];
    const float* Wq = (const float*)d_in[2];
    const float* bq = (const float*)d_in[3];
    const float* Wk = (const float*)d_in[4];
    const float* bk = (const float*)d_in[5];
    const float* Wv = (const float*)d_in[6];
    const float* bv = (const float*)d_in[7];
    const float* Wo = (const float*)d_in[8];
    const float* bo = (const float*)d_in[9];

    float* out = (float*)d_out;
    float* P   = out + (size_t)M * D;

    char* ws = (char*)d_ws;
    const size_t MB = 1u << 20;
    unsigned short* xb    = (unsigned short*)(ws);            // 8 MB
    unsigned short* WtAll = (unsigned short*)(ws + 8 * MB);   // 8 MB  [Wq|Wk|Wv|Wo] transposed
    unsigned short* Qb    = (unsigned short*)(ws + 16 * MB);  // 8 MB
    unsigned short* Kb    = (unsigned short*)(ws + 24 * MB);  // 8 MB
    unsigned short* Vtb   = (unsigned short*)(ws + 32 * MB);  // 8 MB  [bh][dh][s]
    unsigned short* ctxb  = (unsigned short*)(ws + 40 * MB);  // 8 MB

    const dim3 blk(256);

    pack_x<<<dim3(M * D / (256 * 8)), blk, 0, stream>>>(x, xb);
    transpose_w4<<<dim3(16, 16, 4), blk, 0, stream>>>(Wq, Wk, Wv, Wo, WtAll);

    // fused QKV projection (768 blocks) + P upper-tri zero-fill (512 blocks)
    qkv_zero<<<dim3(1280), blk, 0, stream>>>(
        xb, WtAll, bq, bk, bv, Qb, Kb, Vtb, P);

    // fused attention: rowsum (sweep 1, in-register) + P + PV (sweep 2)
    attn_fused<<<dim3(B * H, S / 64), blk, 0, stream>>>(Qb, Kb, Vtb, P, ctxb);

    // output projection
    out_gemm<<<dim3(8, M / 128), blk, 0, stream>>>(
        ctxb, WtAll + (size_t)3 * D * D, bo, out);
}

// Round 12
// 289.257 us; speedup vs baseline: 1.1947x; 1.1947x over previous
//
#include <hip/hip_runtime.h>
#include <cstdint>

namespace {

typedef __attribute__((ext_vector_type(8))) short bf16x8;
typedef __attribute__((ext_vector_type(4))) short bf16x4;
typedef __attribute__((ext_vector_type(4))) float f32x4;

constexpr int D  = 1024;
constexpr int H  = 16;
constexpr int DH = 64;
constexpr int B  = 2;
constexpr int S  = 2048;
constexpr int M  = B * S;          // 4096
// 1/sqrt(64) * log2(e): QK^T logits land pre-scaled for exp2
constexpr float SCALE_Q = 0.125f * 1.4426950408889634f;

__device__ inline unsigned short f2bf(float f) {
    union { float f; uint32_t u; } v{f};
    return (unsigned short)((v.u + 0x7fffu + ((v.u >> 16) & 1u)) >> 16);
}

__device__ inline void gload16(const void* g, void* l) {
    __builtin_amdgcn_global_load_lds(
        (const __attribute__((address_space(1))) void*)g,
        (__attribute__((address_space(3))) void*)l, 16, 0, 0);
}

// ---------------------------------------------------------------------------
// x [4096,1024] f32 -> bf16
// ---------------------------------------------------------------------------
__global__ __launch_bounds__(256) void pack_x(const float* __restrict__ x,
                                              unsigned short* __restrict__ xb) {
    const int i = (blockIdx.x * 256 + threadIdx.x) * 8;
    float4 a = *reinterpret_cast<const float4*>(&x[i]);
    float4 b = *reinterpret_cast<const float4*>(&x[i + 4]);
    bf16x8 o;
    o[0] = f2bf(a.x); o[1] = f2bf(a.y); o[2] = f2bf(a.z); o[3] = f2bf(a.w);
    o[4] = f2bf(b.x); o[5] = f2bf(b.y); o[6] = f2bf(b.z); o[7] = f2bf(b.w);
    *reinterpret_cast<bf16x8*>(&xb[i]) = o;
}

// ---------------------------------------------------------------------------
// 4 weight matrices [1024 k][1024 n] f32 -> WtAll bf16 [4][n][k]
// ---------------------------------------------------------------------------
__global__ __launch_bounds__(256) void transpose_w4(
    const float* __restrict__ W0, const float* __restrict__ W1,
    const float* __restrict__ W2, const float* __restrict__ W3,
    unsigned short* __restrict__ WtAll)
{
    __shared__ unsigned short T[64][72];
    const int z = blockIdx.z;
    const float* W = z == 0 ? W0 : (z == 1 ? W1 : (z == 2 ? W2 : W3));
    unsigned short* Wt = WtAll + (size_t)z * D * D;
    const int n0 = blockIdx.x * 64, k0 = blockIdx.y * 64;
    const int t = threadIdx.x;
    #pragma unroll
    for (int i = 0; i < 16; ++i) {
        int idx = i * 256 + t, r = idx >> 6, c = idx & 63;
        T[r][c] = f2bf(W[(size_t)(k0 + r) * D + n0 + c]);
    }
    __syncthreads();
    #pragma unroll
    for (int i = 0; i < 16; ++i) {
        int idx = i * 256 + t, r = idx >> 6, c = idx & 63;
        Wt[(size_t)(n0 + r) * D + k0 + c] = T[c][r];
    }
}

// ---------------------------------------------------------------------------
// MFMA GEMM, m97 structure: global_load_lds(16B) + XOR-swizzled linear LDS.
// C[M,N] = A[M,K] @ Bt[N,K]^T + bias.  128x128 tile, BK=64, 4 waves (2x2).
// MODE 0: fused QKV (N=3072): Q (scaled SCALE_Q incl. log2e), K -> split-head
//         bf16; V -> Vt[bh][dh][s] bf16 DIRECTLY (transpose in epilogue).
// MODE 1: fp32 row-major out (final projection, N=1024).
// ---------------------------------------------------------------------------
template <int MODE>
__global__ __launch_bounds__(256) void mfma_gemm(
    const unsigned short* __restrict__ A, const unsigned short* __restrict__ Bt,
    const float* __restrict__ b0, const float* __restrict__ b1,
    const float* __restrict__ b2,
    unsigned short* __restrict__ oQ, unsigned short* __restrict__ oK,
    unsigned short* __restrict__ oVt, float* __restrict__ oF)
{
    __shared__ __align__(16) unsigned short As[128 * 64];
    __shared__ __align__(16) unsigned short Bs[128 * 64];
    const int t = threadIdx.x;
    const int lane = t & 63, w = t >> 6;
    const int wr = w >> 1, wc = w & 1;
    const int lo = lane & 15, hi = lane >> 4;
    const int m0 = blockIdx.y * 128, n0 = blockIdx.x * 128;

    f32x4 acc[4][4] = {};

    for (int k0 = 0; k0 < D; k0 += 64) {
        #pragma unroll
        for (int i = 0; i < 4; ++i) {
            const int row = i * 32 + w * 8 + (lane >> 3);
            const int gcol = ((lane & 7) * 8) ^ ((row & 7) * 8);  // src pre-swizzle
            gload16(&A[(size_t)(m0 + row) * D + k0 + gcol], &As[i * 2048 + w * 512]);
            gload16(&Bt[(size_t)(n0 + row) * D + k0 + gcol], &Bs[i * 2048 + w * 512]);
        }
        __syncthreads();
        #pragma unroll
        for (int kk = 0; kk < 2; ++kk) {
            bf16x8 a[4], b[4];
            #pragma unroll
            for (int m = 0; m < 4; ++m) {
                const int row = wr * 64 + m * 16 + lo;
                a[m] = *reinterpret_cast<const bf16x8*>(
                    &As[row * 64 + ((kk * 32 + hi * 8) ^ ((row & 7) * 8))]);
            }
            #pragma unroll
            for (int n = 0; n < 4; ++n) {
                const int row = wc * 64 + n * 16 + lo;
                b[n] = *reinterpret_cast<const bf16x8*>(
                    &Bs[row * 64 + ((kk * 32 + hi * 8) ^ ((row & 7) * 8))]);
            }
            #pragma unroll
            for (int m = 0; m < 4; ++m)
                #pragma unroll
                for (int n = 0; n < 4; ++n)
                    acc[m][n] = __builtin_amdgcn_mfma_f32_16x16x32_bf16(a[m], b[n], acc[m][n], 0, 0, 0);
        }
        __syncthreads();
    }

    // acc[m][n][r]: row = m0+wr*64+m*16+hi*4+r, col = n0+wc*64+n*16+lo
    if (MODE == 0) {
        const int which = n0 >> 10;                 // uniform per block
        if (which == 2) {
            // V: write Vt[bh][dh][s] directly; 4 consecutive s per lane -> bf16x4
            #pragma unroll
            for (int m = 0; m < 4; ++m) {
                const int row0 = m0 + wr * 64 + m * 16 + hi * 4;
                const int b_ = row0 >> 11, s_ = row0 & (S - 1);
                #pragma unroll
                for (int n = 0; n < 4; ++n) {
                    const int nn = (n0 + wc * 64 + n * 16 + lo) & 1023;
                    const int h_ = nn >> 6, dh = nn & 63;
                    const float bcol = b2[nn];
                    bf16x4 o;
                    #pragma unroll
                    for (int r = 0; r < 4; ++r) o[r] = (short)f2bf(acc[m][n][r] + bcol);
                    *reinterpret_cast<bf16x4*>(
                        &oVt[((size_t)(b_ * H + h_) * DH + dh) * S + s_]) = o;
                }
            }
        } else {
            const float* bs = which == 0 ? b0 : b1;
            unsigned short* op = which == 0 ? oQ : oK;
            const float scale = which == 0 ? SCALE_Q : 1.0f;
            #pragma unroll
            for (int m = 0; m < 4; ++m)
                #pragma unroll
                for (int n = 0; n < 4; ++n) {
                    const int nn = (n0 + wc * 64 + n * 16 + lo) & 1023;
                    const float bcol = bs[nn];
                    const int h_ = nn >> 6, dh = nn & 63;
                    #pragma unroll
                    for (int r = 0; r < 4; ++r) {
                        const int row = m0 + wr * 64 + m * 16 + hi * 4 + r;
                        const int b_ = row >> 11, s_ = row & (S - 1);
                        op[(((size_t)(b_ * H + h_) * S) + s_) * DH + dh] =
                            f2bf((acc[m][n][r] + bcol) * scale);
                    }
                }
        }
    } else {
        #pragma unroll
        for (int m = 0; m < 4; ++m)
            #pragma unroll
            for (int n = 0; n < 4; ++n) {
                const int col = n0 + wc * 64 + n * 16 + lo;
                const float bcol = b0[col];
                #pragma unroll
                for (int r = 0; r < 4; ++r) {
                    const int row = m0 + wr * 64 + m * 16 + hi * 4 + r;
                    oF[(size_t)row * D + col] = acc[m][n][r] + bcol;
                }
            }
    }
}

// ---------------------------------------------------------------------------
// Fused attention (Q pre-scaled by log2e -> exp2f; diag tile peeled).
// Sweep 1: row 1/sumexp in registers. Sweep 2: recompute QK^T, normalized P
// via dbuf LDS stage -> coalesced 4-row x 256B nontemporal stores, PV from
// the same LDS tile, then upper-tri zero-fill (the write-work counterweight).
// qt remapped so each CU's 4 resident blocks sum to 62 compute-tiles AND 62
// zero-tiles: both MFMA and store work constant per CU (makespan = average).
// ---------------------------------------------------------------------------
__global__ __launch_bounds__(256) void attn_fused(
    const unsigned short* __restrict__ Q, const unsigned short* __restrict__ K,
    const unsigned short* __restrict__ Vt, float* __restrict__ P,
    unsigned short* __restrict__ ctxb)
{
    __shared__ __align__(16) float Pf[2][4][16][68];
    const int bh = blockIdx.x;
    // balanced qt map: chunks of 8 y-values -> {31-j, j, 23-j, 8+j}
    const int y = blockIdx.y;
    const int jy = y & 7, ky = y >> 3;
    const int qt = (ky == 0) ? 31 - jy : (ky == 1) ? jy : (ky == 2) ? 23 - jy : 8 + jy;
    const int t = threadIdx.x, lane = t & 63, w = t >> 6;
    const int lo = lane & 15, hi = lane >> 4;
    const int q0 = qt * 64 + w * 16;
    const unsigned short* Qb = Q + (size_t)bh * S * DH;
    const unsigned short* Kb = K + (size_t)bh * S * DH;
    const unsigned short* Vb = Vt + (size_t)bh * DH * S;
    float* Pb = P + (size_t)bh * S * S;

    bf16x8 aq[2];
    #pragma unroll
    for (int kk = 0; kk < 2; ++kk)
        aq[kk] = *reinterpret_cast<const bf16x8*>(&Qb[(size_t)(q0 + lo) * DH + kk * 32 + hi * 8]);

    // ---- sweep 1: row sums (registers only); diag tile peeled
    float li[4];
    {
        float rsum[4] = {0.f, 0.f, 0.f, 0.f};
        for (int jt = 0; jt < qt; ++jt) {         // mask-free main loop
            f32x4 acc[4] = {};
            #pragma unroll
            for (int kk = 0; kk < 2; ++kk)
                #pragma unroll
                for (int n = 0; n < 4; ++n) {
                    bf16x8 bk = *reinterpret_cast<const bf16x8*>(
                        &Kb[(size_t)(jt * 64 + n * 16 + lo) * DH + kk * 32 + hi * 8]);
                    acc[n] = __builtin_amdgcn_mfma_f32_16x16x32_bf16(aq[kk], bk, acc[n], 0, 0, 0);
                }
            #pragma unroll
            for (int n = 0; n < 4; ++n)
                #pragma unroll
                for (int r = 0; r < 4; ++r) rsum[r] += exp2f(acc[n][r]);
        }
        {   // diag tile (jt == qt), masked
            f32x4 acc[4] = {};
            #pragma unroll
            for (int kk = 0; kk < 2; ++kk)
                #pragma unroll
                for (int n = 0; n < 4; ++n) {
                    bf16x8 bk = *reinterpret_cast<const bf16x8*>(
                        &Kb[(size_t)(qt * 64 + n * 16 + lo) * DH + kk * 32 + hi * 8]);
                    acc[n] = __builtin_amdgcn_mfma_f32_16x16x32_bf16(aq[kk], bk, acc[n], 0, 0, 0);
                }
            #pragma unroll
            for (int n = 0; n < 4; ++n) {
                const int j = qt * 64 + n * 16 + lo;
                #pragma unroll
                for (int r = 0; r < 4; ++r) {
                    const float e = exp2f(acc[n][r]);
                    rsum[r] += (j > q0 + hi * 4 + r) ? 0.f : e;
                }
            }
        }
        #pragma unroll
        for (int r = 0; r < 4; ++r) {
            #pragma unroll
            for (int off = 1; off < 16; off <<= 1) rsum[r] += __shfl_xor(rsum[r], off);
            li[r] = 1.0f / rsum[r];      // every lane holds its (hi,r) row's sum
        }
    }

    // ---- sweep 2: normalized P + PV context; diag tile peeled
    f32x4 actx[4] = {};

    for (int jt = 0; jt <= qt; ++jt) {
        float (*pf)[68] = Pf[jt & 1][w];
        f32x4 acc[4] = {};
        #pragma unroll
        for (int kk = 0; kk < 2; ++kk)
            #pragma unroll
            for (int n = 0; n < 4; ++n) {
                bf16x8 bk = *reinterpret_cast<const bf16x8*>(
                    &Kb[(size_t)(jt * 64 + n * 16 + lo) * DH + kk * 32 + hi * 8]);
                acc[n] = __builtin_amdgcn_mfma_f32_16x16x32_bf16(aq[kk], bk, acc[n], 0, 0, 0);
            }
        if (jt < qt) {                            // mask-free path
            #pragma unroll
            for (int n = 0; n < 4; ++n)
                #pragma unroll
                for (int r = 0; r < 4; ++r)
                    pf[hi * 4 + r][n * 16 + lo] = exp2f(acc[n][r]) * li[r];
        } else {                                  // diag tile, masked
            #pragma unroll
            for (int n = 0; n < 4; ++n) {
                const int j = qt * 64 + n * 16 + lo;
                #pragma unroll
                for (int r = 0; r < 4; ++r) {
                    const int qrow = q0 + hi * 4 + r;
                    float p = exp2f(acc[n][r]) * li[r];
                    pf[hi * 4 + r][n * 16 + lo] = (j > qrow) ? 0.f : p;
                }
            }
        }
        // coalesced nontemporal f32x4 stores of the 16x64 fp32 tile
        #pragma unroll
        for (int i2 = 0; i2 < 4; ++i2) {
            const int row = i2 * 4 + hi;
            f32x4 v = *reinterpret_cast<const f32x4*>(&pf[row][lo * 4]);
            __builtin_nontemporal_store(
                v, reinterpret_cast<f32x4*>(&Pb[(size_t)(q0 + row) * S + jt * 64 + lo * 4]));
        }
        // PV: A-frag rebuilt from LDS fp32 (row=lo, k=kk*32+hi*8..+8)
        #pragma unroll
        for (int kk = 0; kk < 2; ++kk) {
            const float* src = &pf[lo][kk * 32 + hi * 8];
            float4 f0 = *reinterpret_cast<const float4*>(src);
            float4 f1 = *reinterpret_cast<const float4*>(src + 4);
            bf16x8 pa;
            pa[0] = f2bf(f0.x); pa[1] = f2bf(f0.y); pa[2] = f2bf(f0.z); pa[3] = f2bf(f0.w);
            pa[4] = f2bf(f1.x); pa[5] = f2bf(f1.y); pa[6] = f2bf(f1.z); pa[7] = f2bf(f1.w);
            #pragma unroll
            for (int n2 = 0; n2 < 4; ++n2) {
                bf16x8 bv = *reinterpret_cast<const bf16x8*>(
                    &Vb[(size_t)(n2 * 16 + lo) * S + jt * 64 + kk * 32 + hi * 8]);
                actx[n2] = __builtin_amdgcn_mfma_f32_16x16x32_bf16(pa, bv, actx[n2], 0, 0, 0);
            }
        }
    }

    // zero-fill strictly-upper tiles of P
    const f32x4 z = {0.f, 0.f, 0.f, 0.f};
    for (int jt = qt + 1; jt < S / 64; ++jt)
        #pragma unroll
        for (int rr = 0; rr < 4; ++rr) {
            const int qrow = q0 + rr * 4 + hi;
            __builtin_nontemporal_store(
                z, reinterpret_cast<f32x4*>(&Pb[(size_t)qrow * S + jt * 64 + lo * 4]));
        }

    // ctx -> merged-head bf16 [b*S+q][h*64+dh]
    const int b_ = bh >> 4, h_ = bh & 15;
    #pragma unroll
    for (int n2 = 0; n2 < 4; ++n2)
        #pragma unroll
        for (int r = 0; r < 4; ++r) {
            const int qg = q0 + hi * 4 + r;
            ctxb[((size_t)(b_ * S + qg)) * D + h_ * 64 + n2 * 16 + lo] = f2bf(actx[n2][r]);
        }
}

}  // namespace

extern "C" void kernel_launch(void* const* d_in, const int* in_sizes, int n_in,
                              void* d_out, int out_size, void* d_ws, size_t ws_size,
                              hipStream_t stream) {
    const float* x  = (const float*)d_in[0];
    const float* Wq = (const float*)d_in[2];
    const float* bq = (const float*)d_in[3];
    const float* Wk = (const float*)d_in[4];
    const float* bk = (const float*)d_in[5];
    const float* Wv = (const float*)d_in[6];
    const float* bv = (const float*)d_in[7];
    const float* Wo = (const float*)d_in[8];
    const float* bo = (const float*)d_in[9];

    float* out = (float*)d_out;
    float* P   = out + (size_t)M * D;

    char* ws = (char*)d_ws;
    const size_t MB = 1u << 20;
    unsigned short* xb    = (unsigned short*)(ws);            // 8 MB
    unsigned short* WtAll = (unsigned short*)(ws + 8 * MB);   // 8 MB  [Wq|Wk|Wv|Wo] transposed
    unsigned short* Qb    = (unsigned short*)(ws + 16 * MB);  // 8 MB
    unsigned short* Kb    = (unsigned short*)(ws + 24 * MB);  // 8 MB
    unsigned short* Vtb   = (unsigned short*)(ws + 32 * MB);  // 8 MB  [bh][dh][s]
    unsigned short* ctxb  = (unsigned short*)(ws + 40 * MB);  // 8 MB

    const dim3 blk(256);

    pack_x<<<dim3(M * D / (256 * 8)), blk, 0, stream>>>(x, xb);
    transpose_w4<<<dim3(16, 16, 4), blk, 0, stream>>>(Wq, Wk, Wv, Wo, WtAll);

    // fused QKV projection: N = 3072; V written directly transposed
    mfma_gemm<0><<<dim3(24, M / 128), blk, 0, stream>>>(
        xb, WtAll, bq, bk, bv, Qb, Kb, Vtb, nullptr);

    // fused attention: rowsum (sweep 1, in-register) + P + PV (sweep 2)
    attn_fused<<<dim3(B * H, S / 64), blk, 0, stream>>>(Qb, Kb, Vtb, P, ctxb);

    // output projection
    mfma_gemm<1><<<dim3(8, M / 128), blk, 0, stream>>>(
        ctxb, WtAll + (size_t)3 * D * D, bo, nullptr, nullptr,
        nullptr, nullptr, nullptr, out);
}

// Round 13
// 242.530 us; speedup vs baseline: 1.4249x; 1.1927x over previous
//
#include <hip/hip_runtime.h>
#include <cstdint>

namespace {

typedef __attribute__((ext_vector_type(8))) short bf16x8;
typedef __attribute__((ext_vector_type(4))) short bf16x4;
typedef __attribute__((ext_vector_type(4))) float f32x4;

constexpr int D  = 1024;
constexpr int H  = 16;
constexpr int DH = 64;
constexpr int B  = 2;
constexpr int S  = 2048;
constexpr int M  = B * S;          // 4096
// 1/sqrt(64) * log2(e): QK^T logits land pre-scaled for exp2
constexpr float SCALE_Q = 0.125f * 1.4426950408889634f;

__device__ inline unsigned short f2bf(float f) {
    union { float f; uint32_t u; } v{f};
    return (unsigned short)((v.u + 0x7fffu + ((v.u >> 16) & 1u)) >> 16);
}

__device__ inline void gload16(const void* g, void* l) {
    __builtin_amdgcn_global_load_lds(
        (const __attribute__((address_space(1))) void*)g,
        (__attribute__((address_space(3))) void*)l, 16, 0, 0);
}

// ---------------------------------------------------------------------------
// x [4096,1024] f32 -> bf16
// ---------------------------------------------------------------------------
__global__ __launch_bounds__(256) void pack_x(const float* __restrict__ x,
                                              unsigned short* __restrict__ xb) {
    const int i = (blockIdx.x * 256 + threadIdx.x) * 8;
    float4 a = *reinterpret_cast<const float4*>(&x[i]);
    float4 b = *reinterpret_cast<const float4*>(&x[i + 4]);
    bf16x8 o;
    o[0] = f2bf(a.x); o[1] = f2bf(a.y); o[2] = f2bf(a.z); o[3] = f2bf(a.w);
    o[4] = f2bf(b.x); o[5] = f2bf(b.y); o[6] = f2bf(b.z); o[7] = f2bf(b.w);
    *reinterpret_cast<bf16x8*>(&xb[i]) = o;
}

// ---------------------------------------------------------------------------
// 4 weight matrices [1024 k][1024 n] f32 -> WtAll bf16 [4][n][k]
// ---------------------------------------------------------------------------
__global__ __launch_bounds__(256) void transpose_w4(
    const float* __restrict__ W0, const float* __restrict__ W1,
    const float* __restrict__ W2, const float* __restrict__ W3,
    unsigned short* __restrict__ WtAll)
{
    __shared__ unsigned short T[64][72];
    const int z = blockIdx.z;
    const float* W = z == 0 ? W0 : (z == 1 ? W1 : (z == 2 ? W2 : W3));
    unsigned short* Wt = WtAll + (size_t)z * D * D;
    const int n0 = blockIdx.x * 64, k0 = blockIdx.y * 64;
    const int t = threadIdx.x;
    #pragma unroll
    for (int i = 0; i < 16; ++i) {
        int idx = i * 256 + t, r = idx >> 6, c = idx & 63;
        T[r][c] = f2bf(W[(size_t)(k0 + r) * D + n0 + c]);
    }
    __syncthreads();
    #pragma unroll
    for (int i = 0; i < 16; ++i) {
        int idx = i * 256 + t, r = idx >> 6, c = idx & 63;
        Wt[(size_t)(n0 + r) * D + k0 + c] = T[c][r];
    }
}

// ---------------------------------------------------------------------------
// MFMA GEMM, m97 structure: global_load_lds(16B) + XOR-swizzled linear LDS.
// C[M,N] = A[M,K] @ Bt[N,K]^T + bias.  128x128 tile, BK=64, 4 waves (2x2).
// MODE 0: fused QKV (N=3072): Q (scaled SCALE_Q incl. log2e), K -> split-head
//         bf16; V -> Vt[bh][dh][s] bf16 DIRECTLY (transpose in epilogue).
// MODE 1: fp32 row-major out (final projection, N=1024).
// ---------------------------------------------------------------------------
template <int MODE>
__global__ __launch_bounds__(256) void mfma_gemm(
    const unsigned short* __restrict__ A, const unsigned short* __restrict__ Bt,
    const float* __restrict__ b0, const float* __restrict__ b1,
    const float* __restrict__ b2,
    unsigned short* __restrict__ oQ, unsigned short* __restrict__ oK,
    unsigned short* __restrict__ oVt, float* __restrict__ oF)
{
    __shared__ __align__(16) unsigned short As[128 * 64];
    __shared__ __align__(16) unsigned short Bs[128 * 64];
    const int t = threadIdx.x;
    const int lane = t & 63, w = t >> 6;
    const int wr = w >> 1, wc = w & 1;
    const int lo = lane & 15, hi = lane >> 4;
    const int m0 = blockIdx.y * 128, n0 = blockIdx.x * 128;

    f32x4 acc[4][4] = {};

    for (int k0 = 0; k0 < D; k0 += 64) {
        #pragma unroll
        for (int i = 0; i < 4; ++i) {
            const int row = i * 32 + w * 8 + (lane >> 3);
            const int gcol = ((lane & 7) * 8) ^ ((row & 7) * 8);  // src pre-swizzle
            gload16(&A[(size_t)(m0 + row) * D + k0 + gcol], &As[i * 2048 + w * 512]);
            gload16(&Bt[(size_t)(n0 + row) * D + k0 + gcol], &Bs[i * 2048 + w * 512]);
        }
        __syncthreads();
        #pragma unroll
        for (int kk = 0; kk < 2; ++kk) {
            bf16x8 a[4], b[4];
            #pragma unroll
            for (int m = 0; m < 4; ++m) {
                const int row = wr * 64 + m * 16 + lo;
                a[m] = *reinterpret_cast<const bf16x8*>(
                    &As[row * 64 + ((kk * 32 + hi * 8) ^ ((row & 7) * 8))]);
            }
            #pragma unroll
            for (int n = 0; n < 4; ++n) {
                const int row = wc * 64 + n * 16 + lo;
                b[n] = *reinterpret_cast<const bf16x8*>(
                    &Bs[row * 64 + ((kk * 32 + hi * 8) ^ ((row & 7) * 8))]);
            }
            #pragma unroll
            for (int m = 0; m < 4; ++m)
                #pragma unroll
                for (int n = 0; n < 4; ++n)
                    acc[m][n] = __builtin_amdgcn_mfma_f32_16x16x32_bf16(a[m], b[n], acc[m][n], 0, 0, 0);
        }
        __syncthreads();
    }

    // acc[m][n][r]: row = m0+wr*64+m*16+hi*4+r, col = n0+wc*64+n*16+lo
    if (MODE == 0) {
        const int which = n0 >> 10;                 // uniform per block
        if (which == 2) {
            // V: write Vt[bh][dh][s] directly; 4 consecutive s per lane -> bf16x4
            #pragma unroll
            for (int m = 0; m < 4; ++m) {
                const int row0 = m0 + wr * 64 + m * 16 + hi * 4;
                const int b_ = row0 >> 11, s_ = row0 & (S - 1);
                #pragma unroll
                for (int n = 0; n < 4; ++n) {
                    const int nn = (n0 + wc * 64 + n * 16 + lo) & 1023;
                    const int h_ = nn >> 6, dh = nn & 63;
                    const float bcol = b2[nn];
                    bf16x4 o;
                    #pragma unroll
                    for (int r = 0; r < 4; ++r) o[r] = (short)f2bf(acc[m][n][r] + bcol);
                    *reinterpret_cast<bf16x4*>(
                        &oVt[((size_t)(b_ * H + h_) * DH + dh) * S + s_]) = o;
                }
            }
        } else {
            const float* bs = which == 0 ? b0 : b1;
            unsigned short* op = which == 0 ? oQ : oK;
            const float scale = which == 0 ? SCALE_Q : 1.0f;
            #pragma unroll
            for (int m = 0; m < 4; ++m)
                #pragma unroll
                for (int n = 0; n < 4; ++n) {
                    const int nn = (n0 + wc * 64 + n * 16 + lo) & 1023;
                    const float bcol = bs[nn];
                    const int h_ = nn >> 6, dh = nn & 63;
                    #pragma unroll
                    for (int r = 0; r < 4; ++r) {
                        const int row = m0 + wr * 64 + m * 16 + hi * 4 + r;
                        const int b_ = row >> 11, s_ = row & (S - 1);
                        op[(((size_t)(b_ * H + h_) * S) + s_) * DH + dh] =
                            f2bf((acc[m][n][r] + bcol) * scale);
                    }
                }
        }
    } else {
        #pragma unroll
        for (int m = 0; m < 4; ++m)
            #pragma unroll
            for (int n = 0; n < 4; ++n) {
                const int col = n0 + wc * 64 + n * 16 + lo;
                const float bcol = b0[col];
                #pragma unroll
                for (int r = 0; r < 4; ++r) {
                    const int row = m0 + wr * 64 + m * 16 + hi * 4 + r;
                    oF[(size_t)row * D + col] = acc[m][n][r] + bcol;
                }
            }
    }
}

// ---------------------------------------------------------------------------
// Fused attention, 32 q-rows per wave (2 Q-fragments): every K/V fragment
// load feeds 2 MFMAs -> per-jt global loads halved vs 16-row waves.
// Block = 4 waves x 32 rows = 128 q-rows; grid (32 bh, 16 Qt) = 512 blocks
// = 2/CU; Qt paired (15-y, y-8) so per-CU compute (36 jt) and zero-fill (62
// tiles) are constant. Sweep 1: row 1/sumexp in registers (exp2, Q
// pre-scaled by log2e). Sweep 2: recompute QK^T, normalized P via dbuf LDS
// stage -> coalesced 8x(4-row x 256B) nontemporal stores, PV from same tile.
// Per-wave diag jt differs (waves 0,1: 2Qt; waves 2,3: 2Qt+1) — no barriers,
// LDS is wave-private.
// ---------------------------------------------------------------------------
__global__ __launch_bounds__(256) void attn_fused(
    const unsigned short* __restrict__ Q, const unsigned short* __restrict__ K,
    const unsigned short* __restrict__ Vt, float* __restrict__ P,
    unsigned short* __restrict__ ctxb)
{
    __shared__ __align__(16) float Pf[2][4][32][68];
    const int bh = blockIdx.x;
    const int y = blockIdx.y;
    const int Qt = (y < 8) ? 15 - y : y - 8;        // heavy first + CU-paired
    const int t = threadIdx.x, lane = t & 63, w = t >> 6;
    const int lo = lane & 15, hi = lane >> 4;
    const int qw = Qt * 128 + w * 32;               // wave's first q-row
    const int jt_w = (qw + 31) >> 6;                // wave's diagonal jt
    const unsigned short* Qb = Q + (size_t)bh * S * DH;
    const unsigned short* Kb = K + (size_t)bh * S * DH;
    const unsigned short* Vb = Vt + (size_t)bh * DH * S;
    float* Pb = P + (size_t)bh * S * S;

    bf16x8 aq[2][2];
    #pragma unroll
    for (int g = 0; g < 2; ++g)
        #pragma unroll
        for (int kk = 0; kk < 2; ++kk)
            aq[g][kk] = *reinterpret_cast<const bf16x8*>(
                &Qb[(size_t)(qw + g * 16 + lo) * DH + kk * 32 + hi * 8]);

    // ---- sweep 1: row sums (registers only); diag tile peeled
    float li[2][4];
    {
        float rsum[2][4] = {};
        for (int jt = 0; jt < jt_w; ++jt) {          // mask-free main loop
            f32x4 acc[2][4] = {};
            #pragma unroll
            for (int kk = 0; kk < 2; ++kk)
                #pragma unroll
                for (int n = 0; n < 4; ++n) {
                    bf16x8 bk = *reinterpret_cast<const bf16x8*>(
                        &Kb[(size_t)(jt * 64 + n * 16 + lo) * DH + kk * 32 + hi * 8]);
                    #pragma unroll
                    for (int g = 0; g < 2; ++g)
                        acc[g][n] = __builtin_amdgcn_mfma_f32_16x16x32_bf16(aq[g][kk], bk, acc[g][n], 0, 0, 0);
                }
            #pragma unroll
            for (int g = 0; g < 2; ++g)
                #pragma unroll
                for (int n = 0; n < 4; ++n)
                    #pragma unroll
                    for (int r = 0; r < 4; ++r) rsum[g][r] += exp2f(acc[g][n][r]);
        }
        {   // diag tile (jt == jt_w), masked
            f32x4 acc[2][4] = {};
            #pragma unroll
            for (int kk = 0; kk < 2; ++kk)
                #pragma unroll
                for (int n = 0; n < 4; ++n) {
                    bf16x8 bk = *reinterpret_cast<const bf16x8*>(
                        &Kb[(size_t)(jt_w * 64 + n * 16 + lo) * DH + kk * 32 + hi * 8]);
                    #pragma unroll
                    for (int g = 0; g < 2; ++g)
                        acc[g][n] = __builtin_amdgcn_mfma_f32_16x16x32_bf16(aq[g][kk], bk, acc[g][n], 0, 0, 0);
                }
            #pragma unroll
            for (int n = 0; n < 4; ++n) {
                const int j = jt_w * 64 + n * 16 + lo;
                #pragma unroll
                for (int g = 0; g < 2; ++g)
                    #pragma unroll
                    for (int r = 0; r < 4; ++r) {
                        const float e = exp2f(acc[g][n][r]);
                        rsum[g][r] += (j > qw + g * 16 + hi * 4 + r) ? 0.f : e;
                    }
            }
        }
        #pragma unroll
        for (int g = 0; g < 2; ++g)
            #pragma unroll
            for (int r = 0; r < 4; ++r) {
                #pragma unroll
                for (int off = 1; off < 16; off <<= 1)
                    rsum[g][r] += __shfl_xor(rsum[g][r], off);
                li[g][r] = 1.0f / rsum[g][r];
            }
    }

    // ---- sweep 2: normalized P + PV context; diag tile peeled
    f32x4 actx[2][4] = {};

    for (int jt = 0; jt <= jt_w; ++jt) {
        float (*pf)[68] = Pf[jt & 1][w];
        f32x4 acc[2][4] = {};
        #pragma unroll
        for (int kk = 0; kk < 2; ++kk)
            #pragma unroll
            for (int n = 0; n < 4; ++n) {
                bf16x8 bk = *reinterpret_cast<const bf16x8*>(
                    &Kb[(size_t)(jt * 64 + n * 16 + lo) * DH + kk * 32 + hi * 8]);
                #pragma unroll
                for (int g = 0; g < 2; ++g)
                    acc[g][n] = __builtin_amdgcn_mfma_f32_16x16x32_bf16(aq[g][kk], bk, acc[g][n], 0, 0, 0);
            }
        if (jt < jt_w) {                             // mask-free path
            #pragma unroll
            for (int g = 0; g < 2; ++g)
                #pragma unroll
                for (int n = 0; n < 4; ++n)
                    #pragma unroll
                    for (int r = 0; r < 4; ++r)
                        pf[g * 16 + hi * 4 + r][n * 16 + lo] = exp2f(acc[g][n][r]) * li[g][r];
        } else {                                     // diag tile, masked
            #pragma unroll
            for (int n = 0; n < 4; ++n) {
                const int j = jt_w * 64 + n * 16 + lo;
                #pragma unroll
                for (int g = 0; g < 2; ++g)
                    #pragma unroll
                    for (int r = 0; r < 4; ++r) {
                        float p = exp2f(acc[g][n][r]) * li[g][r];
                        pf[g * 16 + hi * 4 + r][n * 16 + lo] =
                            (j > qw + g * 16 + hi * 4 + r) ? 0.f : p;
                    }
            }
        }
        // coalesced nontemporal f32x4 stores of the 32x64 fp32 tile
        #pragma unroll
        for (int i2 = 0; i2 < 8; ++i2) {
            const int row = i2 * 4 + hi;
            f32x4 v = *reinterpret_cast<const f32x4*>(&pf[row][lo * 4]);
            __builtin_nontemporal_store(
                v, reinterpret_cast<f32x4*>(&Pb[(size_t)(qw + row) * S + jt * 64 + lo * 4]));
        }
        // PV: A-frags rebuilt from LDS fp32 (row=g*16+lo); bv shared by both g
        #pragma unroll
        for (int kk = 0; kk < 2; ++kk) {
            bf16x8 pa[2];
            #pragma unroll
            for (int g = 0; g < 2; ++g) {
                const float* src = &pf[g * 16 + lo][kk * 32 + hi * 8];
                float4 f0 = *reinterpret_cast<const float4*>(src);
                float4 f1 = *reinterpret_cast<const float4*>(src + 4);
                pa[g][0] = f2bf(f0.x); pa[g][1] = f2bf(f0.y);
                pa[g][2] = f2bf(f0.z); pa[g][3] = f2bf(f0.w);
                pa[g][4] = f2bf(f1.x); pa[g][5] = f2bf(f1.y);
                pa[g][6] = f2bf(f1.z); pa[g][7] = f2bf(f1.w);
            }
            #pragma unroll
            for (int n2 = 0; n2 < 4; ++n2) {
                bf16x8 bv = *reinterpret_cast<const bf16x8*>(
                    &Vb[(size_t)(n2 * 16 + lo) * S + jt * 64 + kk * 32 + hi * 8]);
                #pragma unroll
                for (int g = 0; g < 2; ++g)
                    actx[g][n2] = __builtin_amdgcn_mfma_f32_16x16x32_bf16(pa[g], bv, actx[g][n2], 0, 0, 0);
            }
        }
    }

    // zero-fill strictly-upper tiles of P (this wave's 32 rows)
    const f32x4 z = {0.f, 0.f, 0.f, 0.f};
    for (int jt = jt_w + 1; jt < S / 64; ++jt)
        #pragma unroll
        for (int rr = 0; rr < 8; ++rr) {
            const int qrow = qw + rr * 4 + hi;
            __builtin_nontemporal_store(
                z, reinterpret_cast<f32x4*>(&Pb[(size_t)qrow * S + jt * 64 + lo * 4]));
        }

    // ctx -> merged-head bf16 [b*S+q][h*64+dh]
    const int b_ = bh >> 4, h_ = bh & 15;
    #pragma unroll
    for (int g = 0; g < 2; ++g)
        #pragma unroll
        for (int n2 = 0; n2 < 4; ++n2)
            #pragma unroll
            for (int r = 0; r < 4; ++r) {
                const int qg = qw + g * 16 + hi * 4 + r;
                ctxb[((size_t)(b_ * S + qg)) * D + h_ * 64 + n2 * 16 + lo] = f2bf(actx[g][n2][r]);
            }
}

}  // namespace

extern "C" void kernel_launch(void* const* d_in, const int* in_sizes, int n_in,
                              void* d_out, int out_size, void* d_ws, size_t ws_size,
                              hipStream_t stream) {
    const float* x  = (const float*)d_in[0];
    const float* Wq = (const float*)d_in[2];
    const float* bq = (const float*)d_in[3];
    const float* Wk = (const float*)d_in[4];
    const float* bk = (const float*)d_in[5];
    const float* Wv = (const float*)d_in[6];
    const float* bv = (const float*)d_in[7];
    const float* Wo = (const float*)d_in[8];
    const float* bo = (const float*)d_in[9];

    float* out = (float*)d_out;
    float* P   = out + (size_t)M * D;

    char* ws = (char*)d_ws;
    const size_t MB = 1u << 20;
    unsigned short* xb    = (unsigned short*)(ws);            // 8 MB
    unsigned short* WtAll = (unsigned short*)(ws + 8 * MB);   // 8 MB  [Wq|Wk|Wv|Wo] transposed
    unsigned short* Qb    = (unsigned short*)(ws + 16 * MB);  // 8 MB
    unsigned short* Kb    = (unsigned short*)(ws + 24 * MB);  // 8 MB
    unsigned short* Vtb   = (unsigned short*)(ws + 32 * MB);  // 8 MB  [bh][dh][s]
    unsigned short* ctxb  = (unsigned short*)(ws + 40 * MB);  // 8 MB

    const dim3 blk(256);

    pack_x<<<dim3(M * D / (256 * 8)), blk, 0, stream>>>(x, xb);
    transpose_w4<<<dim3(16, 16, 4), blk, 0, stream>>>(Wq, Wk, Wv, Wo, WtAll);

    // fused QKV projection: N = 3072; V written directly transposed
    mfma_gemm<0><<<dim3(24, M / 128), blk, 0, stream>>>(
        xb, WtAll, bq, bk, bv, Qb, Kb, Vtb, nullptr);

    // fused attention: 32-row waves, 128-row blocks, balanced Qt pairs
    attn_fused<<<dim3(B * H, 16), blk, 0, stream>>>(Qb, Kb, Vtb, P, ctxb);

    // output projection
    mfma_gemm<1><<<dim3(8, M / 128), blk, 0, stream>>>(
        ctxb, WtAll + (size_t)3 * D * D, bo, nullptr, nullptr,
        nullptr, nullptr, nullptr, out);
}